// Round 1
// baseline (1751.424 us; speedup 1.0000x reference)
//
#include <hip/hip_runtime.h>

// Problem constants
#define Bb   64
#define Ss   257
#define Hh   12
#define HDd  64
#define Dd   768
#define Mv   16448        // B*S
#define M2   16512        // 129*128 (padded rows for 128-tiles)
#define NADH 512

typedef unsigned short u16;
typedef float  f32x4 __attribute__((ext_vector_type(4)));
typedef short  s16x8 __attribute__((ext_vector_type(8)));

__device__ __forceinline__ float bf2f(u16 u) {
  unsigned x = ((unsigned)u) << 16;
  return __builtin_bit_cast(float, x);
}
__device__ __forceinline__ u16 f2bf(float f) {
  unsigned x = __builtin_bit_cast(unsigned, f);
  x = x + 0x7fffu + ((x >> 16) & 1u);   // RNE
  return (u16)(x >> 16);
}

// ---------------------------------------------------------------------------
// hidden (Mv x 768 f32) -> bf16, zero-padded to M2 rows
__global__ void k_conv_hidden(const float* __restrict__ src, u16* __restrict__ dst) {
  size_t i4 = (size_t)blockIdx.x * 256 + threadIdx.x;
  size_t e = i4 * 4;
  size_t row = e / Dd;
  float4 v = make_float4(0.f, 0.f, 0.f, 0.f);
  if (row < Mv) v = *(const float4*)(src + e);
  ushort4 o;
  o.x = f2bf(v.x); o.y = f2bf(v.y); o.z = f2bf(v.z); o.w = f2bf(v.w);
  *(ushort4*)(dst + e) = o;
}

// W (768x768 f32, [k][n]) -> Wt bf16 [n][k]  (transposed so GEMM B-operand
// fragments are contiguous along K in LDS)
__global__ void k_transpose_w(const float* __restrict__ W, u16* __restrict__ Wt) {
  __shared__ float tile[32][33];
  const int tx = threadIdx.x & 31, ty = threadIdx.x >> 5;  // 32 x 8
  const int bx = blockIdx.x, by = blockIdx.y;
#pragma unroll
  for (int i = 0; i < 4; ++i)
    tile[ty + i*8][tx] = W[(size_t)(by*32 + ty + i*8)*Dd + bx*32 + tx];
  __syncthreads();
#pragma unroll
  for (int i = 0; i < 4; ++i)
    Wt[(size_t)(bx*32 + ty + i*8)*Dd + by*32 + tx] = f2bf(tile[tx][ty + i*8]);
}

// ---------------------------------------------------------------------------
// bf16 MFMA GEMM: C[M2 x 768] = A[M2 x 768] @ Wt^T + bias, m97-style 128x128
// tile, BK=32, 4 waves in 2x2, reg-staged LDS with 16B-unit XOR swizzle.
template<int OUTBF16>
__global__ __launch_bounds__(256) void k_gemm(
    const u16* __restrict__ A, const u16* __restrict__ Bt,
    const float* __restrict__ bias, void* __restrict__ Cout,
    int Mvalid, const float* lossbuf, float* lossout)
{
  const int N = Dd, K = Dd;
  __shared__ u16 As[128*32];
  __shared__ u16 Bs[128*32];
  const int tid = threadIdx.x;
  const int lane = tid & 63, wave = tid >> 6;
  const int m0 = blockIdx.x * 128, n0 = blockIdx.y * 128;

  if (lossout && blockIdx.x == 0 && blockIdx.y == 0 && tid == 0)
    lossout[0] = lossbuf[0];

  // staging: 512 16B-units per tile (A) + 512 (B); thread owns units tid, tid+256
  const int arow0 = tid >> 2,        auc = tid & 3;
  const int arow1 = (tid >> 2) + 64;
  const u16* agp0 = A  + (size_t)(m0 + arow0) * K + auc * 8;
  const u16* agp1 = A  + (size_t)(m0 + arow1) * K + auc * 8;
  const u16* bgp0 = Bt + (size_t)(n0 + arow0) * K + auc * 8;
  const u16* bgp1 = Bt + (size_t)(n0 + arow1) * K + auc * 8;
  u16* asp0 = As + (arow0*4 + (auc ^ (arow0 & 3))) * 8;
  u16* asp1 = As + (arow1*4 + (auc ^ (arow1 & 3))) * 8;
  u16* bsp0 = Bs + (arow0*4 + (auc ^ (arow0 & 3))) * 8;
  u16* bsp1 = Bs + (arow1*4 + (auc ^ (arow1 & 3))) * 8;

  f32x4 acc[4][4];
#pragma unroll
  for (int i = 0; i < 4; ++i)
#pragma unroll
    for (int j = 0; j < 4; ++j) acc[i][j] = f32x4{0.f, 0.f, 0.f, 0.f};

  const int wr = wave >> 1, wc = wave & 1;
  const int fr = lane & 15, g = lane >> 4;
  const s16x8* afp[4];
  const s16x8* bfp[4];
#pragma unroll
  for (int mi = 0; mi < 4; ++mi) {
    const int rowa = wr*64 + mi*16 + fr;
    afp[mi] = (const s16x8*)(As + (rowa*4 + (g ^ (rowa & 3))) * 8);
    const int rowb = wc*64 + mi*16 + fr;
    bfp[mi] = (const s16x8*)(Bs + (rowb*4 + (g ^ (rowb & 3))) * 8);
  }

  s16x8 ra0 = *(const s16x8*)agp0;
  s16x8 ra1 = *(const s16x8*)agp1;
  s16x8 rb0 = *(const s16x8*)bgp0;
  s16x8 rb1 = *(const s16x8*)bgp1;

  for (int kt = 0; kt < K/32; ++kt) {
    __syncthreads();
    *(s16x8*)asp0 = ra0; *(s16x8*)asp1 = ra1;
    *(s16x8*)bsp0 = rb0; *(s16x8*)bsp1 = rb1;
    __syncthreads();
    if (kt + 1 < K/32) {
      const int o = (kt + 1) * 32;
      ra0 = *(const s16x8*)(agp0 + o);
      ra1 = *(const s16x8*)(agp1 + o);
      rb0 = *(const s16x8*)(bgp0 + o);
      rb1 = *(const s16x8*)(bgp1 + o);
    }
    s16x8 af[4], bf[4];
#pragma unroll
    for (int mi = 0; mi < 4; ++mi) af[mi] = afp[mi][0];
#pragma unroll
    for (int ni = 0; ni < 4; ++ni) bf[ni] = bfp[ni][0];
#pragma unroll
    for (int mi = 0; mi < 4; ++mi)
#pragma unroll
      for (int ni = 0; ni < 4; ++ni)
        acc[mi][ni] = __builtin_amdgcn_mfma_f32_16x16x32_bf16(af[mi], bf[ni], acc[mi][ni], 0, 0, 0);
  }

  // epilogue: C/D layout col = lane&15, row = (lane>>4)*4 + reg
#pragma unroll
  for (int ni = 0; ni < 4; ++ni) {
    const int col = n0 + wc*64 + ni*16 + fr;
    const float bv = bias[col];
#pragma unroll
    for (int mi = 0; mi < 4; ++mi) {
      const int rowb = m0 + wr*64 + mi*16 + (lane >> 4)*4;
#pragma unroll
      for (int r = 0; r < 4; ++r) {
        const int row = rowb + r;
        if (row < Mvalid) {
          const float vv = acc[mi][ni][r] + bv;
          if (OUTBF16) ((u16*)Cout)[(size_t)row*N + col] = f2bf(vv);
          else         ((float*)Cout)[(size_t)row*N + col] = vv;
        }
      }
    }
  }
}

// ---------------------------------------------------------------------------
// Adversarial MLPs + entropy + loss. One block per (b,h), 256 threads.
__global__ __launch_bounds__(256) void k_adv(
    const u16* __restrict__ kbf,
    const float* __restrict__ A1, const float* __restrict__ a1,
    const float* __restrict__ A2, const float* __restrict__ a2,
    const float* __restrict__ B1, const float* __restrict__ b1,
    const float* __restrict__ B2, const float* __restrict__ b2,
    float* __restrict__ ent, float* __restrict__ lossacc)
{
  __shared__ float patch[256*65];
  __shared__ float s2buf[256];
  __shared__ float p2s[64];
  __shared__ float l2s[64];
  __shared__ float red[256];
  const int tid = threadIdx.x;
  const int lane = tid & 63, wave = tid >> 6;
  const int bh = blockIdx.x;
  const int b = bh / Hh, h = bh % Hh;
  const size_t base = (size_t)b * Ss * Dd + (size_t)h * HDd;

  // stage patch = k[b,h,1:,:] as f32 (pad 65 -> conflict-free)
  for (int it = 0; it < 64; ++it) {
    const int n = it*4 + wave;
    patch[n*65 + lane] = bf2f(kbf[base + (size_t)(1 + n)*Dd + lane]);
  }
  __syncthreads();

  // ---- phase A: p1[n] for n = tid; patch row lives in registers
  float pr[64];
#pragma unroll
  for (int f = 0; f < 64; ++f) pr[f] = patch[tid*65 + f];
  float s1 = 0.f;
  for (int kg = 0; kg < NADH; kg += 4) {
    float c0 = a1[kg], c1 = a1[kg+1], c2 = a1[kg+2], c3 = a1[kg+3];
#pragma unroll
    for (int f = 0; f < 64; ++f) {
      const float pvv = pr[f];
      const float* ar = A1 + f*NADH + kg;   // uniform -> s_load_dwordx4
      c0 = fmaf(pvv, ar[0], c0);
      c1 = fmaf(pvv, ar[1], c1);
      c2 = fmaf(pvv, ar[2], c2);
      c3 = fmaf(pvv, ar[3], c3);
    }
    s1 = fmaf(fmaxf(c0, 0.f), A2[kg],   s1);
    s1 = fmaf(fmaxf(c1, 0.f), A2[kg+1], s1);
    s1 = fmaf(fmaxf(c2, 0.f), A2[kg+2], s1);
    s1 = fmaf(fmaxf(c3, 0.f), A2[kg+3], s1);
  }
  const float z1  = s1 + a2[0];
  const float p1q = 1.f / (1.f + __expf(z1));   // = 1 - p1 (sigmoid(-z))
  const float p1  = 1.f - p1q;
  const float l1  = -logf(fmaxf(p1q, 1e-10f));

  // ---- phase B: p2[m] for m = lane; wave owns a 128-wide kk quarter
  const int m = lane;
  const int Rr = m >> 3, Cc = m & 7;
  const int pr0 = Rr*32 + Cc*2;            // (2R)*16 + 2Cc
  const int prow_[4] = {pr0, pr0 + 1, pr0 + 16, pr0 + 17};
  float s2 = 0.f;
  for (int kg = wave*128; kg < wave*128 + 128; kg += 16) {
    float cc[16];
#pragma unroll
    for (int j = 0; j < 16; ++j) cc[j] = b1[kg + j];
#pragma unroll
    for (int part = 0; part < 4; ++part) {
      const float* pb = &patch[prow_[part]*65];
      const float* bb = B1 + (size_t)(part*64)*NADH + kg;
#pragma unroll 8
      for (int f = 0; f < 64; ++f) {
        const float pvv = pb[f];
        const float* br = bb + f*NADH;     // uniform -> scalar loads
#pragma unroll
        for (int j = 0; j < 16; ++j) cc[j] = fmaf(pvv, br[j], cc[j]);
      }
    }
#pragma unroll
    for (int j = 0; j < 16; ++j) s2 = fmaf(fmaxf(cc[j], 0.f), B2[kg + j], s2);
  }
  s2buf[wave*64 + m] = s2;
  __syncthreads();
  if (wave == 0) {
    const float z2  = s2buf[m] + s2buf[64+m] + s2buf[128+m] + s2buf[192+m] + b2[0];
    const float p2q = 1.f / (1.f + __expf(z2));
    p2s[m] = 1.f - p2q;
    l2s[m] = -logf(fmaxf(p2q, 1e-10f));
  }
  __syncthreads();

  // entropy of ad_out, token n = tid
  const int rr = tid >> 4, cc2 = tid & 15;
  const float p2g = p2s[(rr >> 1)*8 + (cc2 >> 1)];
  const float ad  = 0.525f*p1 + 0.475f*p2g;     // (1-LAMDA)p1 + LAMDA*out
  const float entv = -ad*__log2f(ad + 1e-10f) - (1.f - ad)*__log2f(1.f - ad + 1e-10f);
  ent[(size_t)bh*256 + tid] = entv;

  // loss partials
  float lc = l1 * (1.f/196608.f);               // mean over B*H*256
  if (tid < 64) lc += l2s[tid] * (1.f/49152.f); // mean over B*H*64
  red[tid] = lc;
  __syncthreads();
  for (int s = 128; s > 0; s >>= 1) {
    if (tid < s) red[tid] += red[tid + s];
    __syncthreads();
  }
  if (tid == 0) atomicAdd(lossacc, red[0]);
}

// ---------------------------------------------------------------------------
// Fused attention: one block per (b,h), 512 threads. q f32, k/v bf16 global.
// Per 64-row q tile: stage k (f32, pad 66) -> scores+softmax -> p in LDS ->
// restage v into same buffer (pad 68, 260 rows zero-tail) -> PV -> ctx bf16.
__global__ __launch_bounds__(512) void k_attn(
    const float* __restrict__ q, const u16* __restrict__ kbf, const u16* __restrict__ vbf,
    const float* __restrict__ ent, u16* __restrict__ ctxb)
{
  __shared__ float kv[260*68];     // 70720 B
  __shared__ float plds[64*260];   // 66560 B (reused as reduce buffer)
  const int tid = threadIdx.x;
  const int lane = tid & 63, wave = tid >> 6;
  const int bh = blockIdx.x;
  const int b = bh / Hh, h = bh % Hh;
  const size_t base = (size_t)b * Ss * Dd + (size_t)h * HDd;

  int kk[5];
#pragma unroll
  for (int j = 0; j < 5; ++j) { int k = lane + 64*j; kk[j] = (k > 256) ? 256 : k; }
  const bool j4ok = (lane == 0);

  for (int tile = 0; tile < 5; ++tile) {
    const int s0 = tile * 64;
    const int nrows = (Ss - s0) < 64 ? (Ss - s0) : 64;
    __syncthreads();
    // stage K
    for (int e = tid; e < Ss*64; e += 512) {
      const int row = e >> 6, f = e & 63;
      kv[row*66 + f] = bf2f(kbf[base + (size_t)row*Dd + f]);
    }
    __syncthreads();

    // ---- scores + softmax: wave owns 8 q rows
    if (wave*8 < nrows) {
      float acc[8][5];
#pragma unroll
      for (int r = 0; r < 8; ++r)
#pragma unroll
        for (int j = 0; j < 5; ++j) acc[r][j] = 0.f;
      const float* qp[8];
#pragma unroll
      for (int r = 0; r < 8; ++r) {
        int srow = s0 + wave*8 + r; if (srow > 256) srow = 256;
        qp[r] = q + base + (size_t)srow * Dd;
      }
      int kbase[5];
#pragma unroll
      for (int j = 0; j < 5; ++j) kbase[j] = kk[j]*66;

      for (int f = 0; f < 64; f += 2) {
        float2 kf[5];
#pragma unroll
        for (int j = 0; j < 5; ++j) kf[j] = *(const float2*)&kv[kbase[j] + f];
#pragma unroll
        for (int r = 0; r < 8; ++r) {
          const float2 qv = *(const float2*)(qp[r] + f);  // uniform -> s_load
#pragma unroll
          for (int j = 0; j < 5; ++j) {
            acc[r][j] = fmaf(qv.x, kf[j].x, acc[r][j]);
            acc[r][j] = fmaf(qv.y, kf[j].y, acc[r][j]);
          }
        }
      }

#pragma unroll
      for (int r = 0; r < 8; ++r) {
        const int srow = s0 + wave*8 + r;
        if (srow <= 256) {
          float sc[5];
#pragma unroll
          for (int j = 0; j < 5; ++j) sc[j] = acc[r][j] * 0.125f;
          if (!j4ok) sc[4] = -1e30f;
          float mx = fmaxf(fmaxf(fmaxf(sc[0], sc[1]), fmaxf(sc[2], sc[3])), sc[4]);
#pragma unroll
          for (int d = 1; d < 64; d <<= 1) mx = fmaxf(mx, __shfl_xor(mx, d));
          float pj[5]; float sum = 0.f;
#pragma unroll
          for (int j = 0; j < 5; ++j) { pj[j] = __expf(sc[j] - mx); sum += pj[j]; }
#pragma unroll
          for (int d = 1; d < 64; d <<= 1) sum += __shfl_xor(sum, d);
          const float inv = 1.f / sum;
          if (srow == 0) {   // entropy reweighting of query row 0 (post-softmax)
#pragma unroll
            for (int j = 0; j < 5; ++j) {
              const float ef = (kk[j] == 0) ? 1.f : ent[(size_t)bh*256 + (kk[j] - 1)];
              pj[j] *= ef;
            }
          }
          float* prow = &plds[(wave*8 + r) * 260];
#pragma unroll
          for (int j = 0; j < 4; ++j) prow[lane + 64*j] = pj[j] * inv;
          if (lane < 4) prow[256 + lane] = j4ok ? pj[4] * inv : 0.f;
        }
      }
    }
    __syncthreads();
    // stage V (overwrite kv), zero tail rows 257..259
    for (int e = tid; e < 260*64; e += 512) {
      const int row = e >> 6, f = e & 63;
      kv[row*68 + f] = (row < Ss) ? bf2f(vbf[base + (size_t)row*Dd + f]) : 0.f;
    }
    __syncthreads();

    // ---- PV: 8 waves = 4 k-groups x 2 row-groups
    const int kg = wave >> 1, rg = wave & 1;
    const int tx = lane & 15, tyy = lane >> 4;
    float pv[8][4];
#pragma unroll
    for (int i = 0; i < 8; ++i)
#pragma unroll
      for (int jj = 0; jj < 4; ++jj) pv[i][jj] = 0.f;
    for (int g2 = kg; g2 <= 64; g2 += 4) {
      const int k0 = g2 * 4;
      float4 v4[4];
#pragma unroll
      for (int kx = 0; kx < 4; ++kx) v4[kx] = *(const float4*)&kv[(k0 + kx)*68 + tx*4];
#pragma unroll
      for (int i = 0; i < 8; ++i) {
        const float4 p4 = *(const float4*)&plds[(rg*32 + tyy*8 + i)*260 + k0];
        const float pa[4] = {p4.x, p4.y, p4.z, p4.w};
#pragma unroll
        for (int kx = 0; kx < 4; ++kx) {
          pv[i][0] = fmaf(pa[kx], v4[kx].x, pv[i][0]);
          pv[i][1] = fmaf(pa[kx], v4[kx].y, pv[i][1]);
          pv[i][2] = fmaf(pa[kx], v4[kx].z, pv[i][2]);
          pv[i][3] = fmaf(pa[kx], v4[kx].w, pv[i][3]);
        }
      }
    }
    __syncthreads();
    float* red = plds;   // reuse
    if (kg > 0) {
      const int rbase = (((kg - 1)*2 + rg)*64 + lane)*32;
#pragma unroll
      for (int i = 0; i < 8; ++i)
#pragma unroll
        for (int jj = 0; jj < 4; ++jj) red[rbase + i*4 + jj] = pv[i][jj];
    }
    __syncthreads();
    if (kg == 0) {
#pragma unroll
      for (int kgo = 0; kgo < 3; ++kgo) {
        const int rbase = ((kgo*2 + rg)*64 + lane)*32;
#pragma unroll
        for (int i = 0; i < 8; ++i)
#pragma unroll
          for (int jj = 0; jj < 4; ++jj) pv[i][jj] += red[rbase + i*4 + jj];
      }
#pragma unroll
      for (int i = 0; i < 8; ++i) {
        const int r = rg*32 + tyy*8 + i;
        if (r < nrows) {
          ushort4 o;
          o.x = f2bf(pv[i][0]); o.y = f2bf(pv[i][1]);
          o.z = f2bf(pv[i][2]); o.w = f2bf(pv[i][3]);
          *(ushort4*)(ctxb + base + (size_t)(s0 + r)*Dd + tx*4) = o;
        }
      }
    }
  }
}

// ---------------------------------------------------------------------------
extern "C" void kernel_launch(void* const* d_in, const int* in_sizes, int n_in,
                              void* d_out, int out_size, void* d_ws, size_t ws_size,
                              hipStream_t stream) {
  const float* hid = (const float*)d_in[0];
  const float* Wq  = (const float*)d_in[1];
  const float* bq  = (const float*)d_in[2];
  const float* Wk  = (const float*)d_in[3];
  const float* bk  = (const float*)d_in[4];
  const float* Wv  = (const float*)d_in[5];
  const float* bv  = (const float*)d_in[6];
  const float* Wo  = (const float*)d_in[7];
  const float* bo  = (const float*)d_in[8];
  const float* A1  = (const float*)d_in[9];
  const float* a1  = (const float*)d_in[10];
  const float* A2  = (const float*)d_in[11];
  const float* a2  = (const float*)d_in[12];
  const float* B1  = (const float*)d_in[13];
  const float* b1  = (const float*)d_in[14];
  const float* B2  = (const float*)d_in[15];
  const float* b2  = (const float*)d_in[16];

  char* p = (char*)d_ws;
  size_t off = 0;
  auto alloc = [&](size_t bytes) -> void* {
    void* r = p + off; off += (bytes + 255) & ~(size_t)255; return r;
  };
  u16*   hb   = (u16*)  alloc((size_t)M2*Dd*2);
  u16*   wqt  = (u16*)  alloc((size_t)Dd*Dd*2);
  u16*   wkt  = (u16*)  alloc((size_t)Dd*Dd*2);
  u16*   wvt  = (u16*)  alloc((size_t)Dd*Dd*2);
  u16*   wot  = (u16*)  alloc((size_t)Dd*Dd*2);
  float* qf   = (float*)alloc((size_t)M2*Dd*4);
  u16*   kb   = (u16*)  alloc((size_t)M2*Dd*2);
  u16*   vb   = (u16*)  alloc((size_t)M2*Dd*2);
  u16*   ctxb = (u16*)  alloc((size_t)M2*Dd*2);
  float* entw = (float*)alloc((size_t)Bb*Hh*256*4);
  float* lossw = (float*)alloc(256);

  hipMemsetAsync(lossw, 0, 4, stream);
  k_conv_hidden<<<dim3((M2*Dd/4)/256), 256, 0, stream>>>(hid, hb);
  dim3 tg(24, 24);
  k_transpose_w<<<tg, 256, 0, stream>>>(Wq, wqt);
  k_transpose_w<<<tg, 256, 0, stream>>>(Wk, wkt);
  k_transpose_w<<<tg, 256, 0, stream>>>(Wv, wvt);
  k_transpose_w<<<tg, 256, 0, stream>>>(Wo, wot);
  dim3 gg(129, 6);
  k_gemm<0><<<gg, 256, 0, stream>>>(hb, wqt, bq, qf, Mv, nullptr, nullptr);
  k_gemm<1><<<gg, 256, 0, stream>>>(hb, wkt, bk, kb, Mv, nullptr, nullptr);
  k_gemm<1><<<gg, 256, 0, stream>>>(hb, wvt, bv, vb, Mv, nullptr, nullptr);
  k_adv<<<Bb*Hh, 256, 0, stream>>>(kb, A1, a1, A2, a2, B1, b1, B2, b2, entw, lossw);
  k_attn<<<Bb*Hh, 512, 0, stream>>>(qf, kb, vb, entw, ctxb);
  k_gemm<0><<<gg, 256, 0, stream>>>(ctxb, wot, bo, (float*)d_out, Mv,
                                    lossw, ((float*)d_out) + (size_t)Mv*Dd);
}

// Round 3
// 927.196 us; speedup vs baseline: 1.8889x; 1.8889x over previous
//
#include <hip/hip_runtime.h>

// Problem constants
#define Bb   64
#define Ss   257
#define Hh   12
#define HDd  64
#define Dd   768
#define Mv   16448        // B*S
#define M2   16512        // 129*128 (padded rows for 128-tiles)
#define NADH 512

typedef unsigned short u16;
typedef float  f32x4 __attribute__((ext_vector_type(4)));
typedef short  s16x8 __attribute__((ext_vector_type(8)));

__device__ __forceinline__ float bf2f(u16 u) {
  unsigned x = ((unsigned)u) << 16;
  return __builtin_bit_cast(float, x);
}
__device__ __forceinline__ u16 f2bf(float f) {
  unsigned x = __builtin_bit_cast(unsigned, f);
  x = x + 0x7fffu + ((x >> 16) & 1u);   // RNE
  return (u16)(x >> 16);
}

// ---------------------------------------------------------------------------
// hidden (Mv x 768 f32) -> bf16, zero-padded to M2 rows
__global__ void k_conv_hidden(const float* __restrict__ src, u16* __restrict__ dst) {
  size_t i4 = (size_t)blockIdx.x * 256 + threadIdx.x;
  size_t e = i4 * 4;
  size_t row = e / Dd;
  float4 v = make_float4(0.f, 0.f, 0.f, 0.f);
  if (row < Mv) v = *(const float4*)(src + e);
  ushort4 o;
  o.x = f2bf(v.x); o.y = f2bf(v.y); o.z = f2bf(v.z); o.w = f2bf(v.w);
  *(ushort4*)(dst + e) = o;
}

// W (K x N f32, [k][n]) -> Wt bf16 [n][k]  (transposed so GEMM B-operand
// fragments are contiguous along K)
__global__ void k_tconv(const float* __restrict__ W, u16* __restrict__ Wt,
                        int K, int N) {
  __shared__ float tile[32][33];
  const int tx = threadIdx.x & 31, ty = threadIdx.x >> 5;  // 32 x 8
  const int n0 = blockIdx.x * 32, k0 = blockIdx.y * 32;
#pragma unroll
  for (int i = 0; i < 4; ++i)
    tile[ty + i*8][tx] = W[(size_t)(k0 + ty + i*8)*N + n0 + tx];
  __syncthreads();
#pragma unroll
  for (int i = 0; i < 4; ++i)
    Wt[(size_t)(n0 + ty + i*8)*K + k0 + tx] = f2bf(tile[tx][ty + i*8]);
}

// ---------------------------------------------------------------------------
// bf16 MFMA GEMM: C[M2 x 768] = A[M2 x 768] @ Wt^T + bias, m97-style 128x128
// tile, BK=32, 4 waves in 2x2, reg-staged LDS with 16B-unit XOR swizzle.
template<int OUTBF16>
__global__ __launch_bounds__(256) void k_gemm(
    const u16* __restrict__ A, const u16* __restrict__ Bt,
    const float* __restrict__ bias, void* __restrict__ Cout,
    int Mvalid, const float* lossbuf, float* lossout)
{
  const int N = Dd, K = Dd;
  __shared__ u16 As[128*32];
  __shared__ u16 Bs[128*32];
  const int tid = threadIdx.x;
  const int lane = tid & 63, wave = tid >> 6;
  const int m0 = blockIdx.x * 128, n0 = blockIdx.y * 128;

  if (lossout && blockIdx.x == 0 && blockIdx.y == 0 && tid == 0)
    lossout[0] = lossbuf[0];

  const int arow0 = tid >> 2,        auc = tid & 3;
  const int arow1 = (tid >> 2) + 64;
  const u16* agp0 = A  + (size_t)(m0 + arow0) * K + auc * 8;
  const u16* agp1 = A  + (size_t)(m0 + arow1) * K + auc * 8;
  const u16* bgp0 = Bt + (size_t)(n0 + arow0) * K + auc * 8;
  const u16* bgp1 = Bt + (size_t)(n0 + arow1) * K + auc * 8;
  u16* asp0 = As + (arow0*4 + (auc ^ (arow0 & 3))) * 8;
  u16* asp1 = As + (arow1*4 + (auc ^ (arow1 & 3))) * 8;
  u16* bsp0 = Bs + (arow0*4 + (auc ^ (arow0 & 3))) * 8;
  u16* bsp1 = Bs + (arow1*4 + (auc ^ (arow1 & 3))) * 8;

  f32x4 acc[4][4];
#pragma unroll
  for (int i = 0; i < 4; ++i)
#pragma unroll
    for (int j = 0; j < 4; ++j) acc[i][j] = f32x4{0.f, 0.f, 0.f, 0.f};

  const int wr = wave >> 1, wc = wave & 1;
  const int fr = lane & 15, g = lane >> 4;
  const s16x8* afp[4];
  const s16x8* bfp[4];
#pragma unroll
  for (int mi = 0; mi < 4; ++mi) {
    const int rowa = wr*64 + mi*16 + fr;
    afp[mi] = (const s16x8*)(As + (rowa*4 + (g ^ (rowa & 3))) * 8);
    const int rowb = wc*64 + mi*16 + fr;
    bfp[mi] = (const s16x8*)(Bs + (rowb*4 + (g ^ (rowb & 3))) * 8);
  }

  s16x8 ra0 = *(const s16x8*)agp0;
  s16x8 ra1 = *(const s16x8*)agp1;
  s16x8 rb0 = *(const s16x8*)bgp0;
  s16x8 rb1 = *(const s16x8*)bgp1;

  for (int kt = 0; kt < K/32; ++kt) {
    __syncthreads();
    *(s16x8*)asp0 = ra0; *(s16x8*)asp1 = ra1;
    *(s16x8*)bsp0 = rb0; *(s16x8*)bsp1 = rb1;
    __syncthreads();
    if (kt + 1 < K/32) {
      const int o = (kt + 1) * 32;
      ra0 = *(const s16x8*)(agp0 + o);
      ra1 = *(const s16x8*)(agp1 + o);
      rb0 = *(const s16x8*)(bgp0 + o);
      rb1 = *(const s16x8*)(bgp1 + o);
    }
    s16x8 af[4], bf[4];
#pragma unroll
    for (int mi = 0; mi < 4; ++mi) af[mi] = afp[mi][0];
#pragma unroll
    for (int ni = 0; ni < 4; ++ni) bf[ni] = bfp[ni][0];
#pragma unroll
    for (int mi = 0; mi < 4; ++mi)
#pragma unroll
      for (int ni = 0; ni < 4; ++ni)
        acc[mi][ni] = __builtin_amdgcn_mfma_f32_16x16x32_bf16(af[mi], bf[ni], acc[mi][ni], 0, 0, 0);
  }

  // epilogue: C/D layout col = lane&15, row = (lane>>4)*4 + reg
#pragma unroll
  for (int ni = 0; ni < 4; ++ni) {
    const int col = n0 + wc*64 + ni*16 + fr;
    const float bv = bias[col];
#pragma unroll
    for (int mi = 0; mi < 4; ++mi) {
      const int rowb = m0 + wr*64 + mi*16 + (lane >> 4)*4;
#pragma unroll
      for (int r = 0; r < 4; ++r) {
        const int row = rowb + r;
        if (row < Mvalid) {
          const float vv = acc[mi][ni][r] + bv;
          if (OUTBF16) ((u16*)Cout)[(size_t)row*N + col] = f2bf(vv);
          else         ((float*)Cout)[(size_t)row*N + col] = vv;
        }
      }
    }
  }
}

// ---------------------------------------------------------------------------
// Adversarial MLPs via MFMA. One block per (b,h), 256 threads (4 waves).
// patch staged bf16 in LDS (XOR-swizzled 16B units); A1t/B1t are bf16 [n][k]
// in global (L2-resident). Second MLP layer fused into the MFMA epilogue:
// relu(acc + b)[row][col] * W2[col], shfl_xor-reduce over the 16 fr-lanes.
__global__ __launch_bounds__(256) void k_adv2(
    const u16* __restrict__ kbf,
    const u16* __restrict__ A1t, const float* __restrict__ a1,
    const float* __restrict__ A2, const float* __restrict__ a2,
    const u16* __restrict__ B1t, const float* __restrict__ b1,
    const float* __restrict__ B2, const float* __restrict__ b2,
    float* __restrict__ ent, float* __restrict__ lossacc)
{
  __shared__ u16  pb[2048*8];    // 256 rows x 64 bf16, unit = row*8 + (c^(row&7))
  __shared__ float p1s[256], l1s[256];
  __shared__ float s2part[4*64];
  __shared__ float p2s[64], l2s[64];
  __shared__ float red[256];

  const int tid = threadIdx.x;
  const int lane = tid & 63, wave = tid >> 6;
  const int fr = lane & 15, g = lane >> 4;
  const int bh = blockIdx.x;
  const int b = bh / Hh, h = bh % Hh;
  const size_t base = (size_t)b * Ss * Dd + (size_t)h * HDd;

  // stage patch = k[b,h,1:,:] (bf16 copy, swizzled)
#pragma unroll
  for (int it = 0; it < 8; ++it) {
    const int u = it*256 + tid;
    const int row = u >> 3, c = u & 7;
    const s16x8 v = *(const s16x8*)(kbf + base + (size_t)(1 + row)*Dd + c*8);
    *(s16x8*)(pb + (row*8 + (c ^ (row & 7)))*8) = v;
  }
  __syncthreads();

  // ---- phase A: p1 for 256 tokens; wave w owns rows 64w..64w+63, all 512 cols
  {
    s16x8 af[4][2];
#pragma unroll
    for (int mi = 0; mi < 4; ++mi)
#pragma unroll
      for (int kt = 0; kt < 2; ++kt) {
        const int row = wave*64 + mi*16 + fr;
        const int c = kt*4 + g;
        af[mi][kt] = *(const s16x8*)(pb + (row*8 + (c ^ (row & 7)))*8);
      }
    float sp[4][4];
#pragma unroll
    for (int mi = 0; mi < 4; ++mi)
#pragma unroll
      for (int r = 0; r < 4; ++r) sp[mi][r] = 0.f;

    for (int ni = 0; ni < 32; ++ni) {
      const int col = ni*16 + fr;
      f32x4 acc[4];
#pragma unroll
      for (int mi = 0; mi < 4; ++mi) acc[mi] = f32x4{0.f,0.f,0.f,0.f};
#pragma unroll
      for (int kt = 0; kt < 2; ++kt) {
        const s16x8 bfr = *(const s16x8*)(A1t + (size_t)col*64 + kt*32 + g*8);
#pragma unroll
        for (int mi = 0; mi < 4; ++mi)
          acc[mi] = __builtin_amdgcn_mfma_f32_16x16x32_bf16(af[mi][kt], bfr, acc[mi], 0, 0, 0);
      }
      const float c1v = a1[col], w2 = A2[col];
#pragma unroll
      for (int mi = 0; mi < 4; ++mi)
#pragma unroll
        for (int r = 0; r < 4; ++r)
          sp[mi][r] += fmaxf(acc[mi][r] + c1v, 0.f) * w2;
    }
#pragma unroll
    for (int mi = 0; mi < 4; ++mi)
#pragma unroll
      for (int r = 0; r < 4; ++r) {
        float v = sp[mi][r];
        v += __shfl_xor(v, 1); v += __shfl_xor(v, 2);
        v += __shfl_xor(v, 4); v += __shfl_xor(v, 8);
        if (fr == 0) {
          const int row = wave*64 + mi*16 + g*4 + r;
          const float z1 = v + a2[0];
          const float q = 1.f / (1.f + __expf(z1));   // 1 - p1
          p1s[row] = 1.f - q;
          l1s[row] = -__logf(fmaxf(q, 1e-10f));
        }
      }
  }

  // ---- phase B: p2 for 64 merged rows; wave w owns cols 128w..128w+127.
  // merged[m][k]: part p = k>>6, patch row = (m>>3)*32 + (m&7)*2 + (p>>1)*16 + (p&1)
#pragma unroll
  for (int pass = 0; pass < 2; ++pass) {
    s16x8 am[2][8];
#pragma unroll
    for (int mi = 0; mi < 2; ++mi)
#pragma unroll
      for (int kt2 = 0; kt2 < 8; ++kt2) {
        const int m = (pass*2 + mi)*16 + fr;
        const int p = kt2 >> 1;
        const int prow = (m >> 3)*32 + (m & 7)*2 + (p >> 1)*16 + (p & 1);
        const int c = (kt2 & 1)*4 + g;
        am[mi][kt2] = *(const s16x8*)(pb + (prow*8 + (c ^ (prow & 7)))*8);
      }
    float sp2[2][4];
#pragma unroll
    for (int mi = 0; mi < 2; ++mi)
#pragma unroll
      for (int r = 0; r < 4; ++r) sp2[mi][r] = 0.f;

    for (int ni2 = 0; ni2 < 8; ++ni2) {
      const int col = wave*128 + ni2*16 + fr;
      f32x4 acc[2];
#pragma unroll
      for (int mi = 0; mi < 2; ++mi) acc[mi] = f32x4{0.f,0.f,0.f,0.f};
#pragma unroll
      for (int kt2 = 0; kt2 < 8; ++kt2) {
        const s16x8 bfr = *(const s16x8*)(B1t + (size_t)col*256 + kt2*32 + g*8);
#pragma unroll
        for (int mi = 0; mi < 2; ++mi)
          acc[mi] = __builtin_amdgcn_mfma_f32_16x16x32_bf16(am[mi][kt2], bfr, acc[mi], 0, 0, 0);
      }
      const float c1v = b1[col], w2 = B2[col];
#pragma unroll
      for (int mi = 0; mi < 2; ++mi)
#pragma unroll
        for (int r = 0; r < 4; ++r)
          sp2[mi][r] += fmaxf(acc[mi][r] + c1v, 0.f) * w2;
    }
#pragma unroll
    for (int mi = 0; mi < 2; ++mi)
#pragma unroll
      for (int r = 0; r < 4; ++r) {
        float v = sp2[mi][r];
        v += __shfl_xor(v, 1); v += __shfl_xor(v, 2);
        v += __shfl_xor(v, 4); v += __shfl_xor(v, 8);
        if (fr == 0) {
          const int m = (pass*2 + mi)*16 + g*4 + r;
          s2part[wave*64 + m] = v;
        }
      }
  }
  __syncthreads();
  if (tid < 64) {
    const float z2 = s2part[tid] + s2part[64 + tid] + s2part[128 + tid]
                   + s2part[192 + tid] + b2[0];
    const float q = 1.f / (1.f + __expf(z2));
    p2s[tid] = 1.f - q;
    l2s[tid] = -__logf(fmaxf(q, 1e-10f));
  }
  __syncthreads();

  // entropy of ad_out, token n = tid
  const int rr = tid >> 4, cc2 = tid & 15;
  const float p2g = p2s[(rr >> 1)*8 + (cc2 >> 1)];
  const float p1v = p1s[tid];
  const float ad  = 0.525f*p1v + 0.475f*p2g;    // (1-LAMDA)p1 + LAMDA*out
  const float entv = -ad*__log2f(ad + 1e-10f) - (1.f - ad)*__log2f(1.f - ad + 1e-10f);
  ent[(size_t)bh*256 + tid] = entv;

  // loss partials
  float lc = l1s[tid] * (1.f/196608.f);          // mean over B*H*256
  if (tid < 64) lc += l2s[tid] * (1.f/49152.f);  // mean over B*H*64
  red[tid] = lc;
  __syncthreads();
  for (int s = 128; s > 0; s >>= 1) {
    if (tid < s) red[tid] += red[tid + s];
    __syncthreads();
  }
  if (tid == 0) atomicAdd(lossacc, red[0]);
}

// ---------------------------------------------------------------------------
// Fused attention: one block per (b,h), 512 threads. q f32, k/v bf16 global.
__global__ __launch_bounds__(512) void k_attn(
    const float* __restrict__ q, const u16* __restrict__ kbf, const u16* __restrict__ vbf,
    const float* __restrict__ ent, u16* __restrict__ ctxb)
{
  __shared__ float kv[260*68];     // 70720 B
  __shared__ float plds[64*260];   // 66560 B (reused as reduce buffer)
  const int tid = threadIdx.x;
  const int lane = tid & 63, wave = tid >> 6;
  const int bh = blockIdx.x;
  const int b = bh / Hh, h = bh % Hh;
  const size_t base = (size_t)b * Ss * Dd + (size_t)h * HDd;

  int kk[5];
#pragma unroll
  for (int j = 0; j < 5; ++j) { int k = lane + 64*j; kk[j] = (k > 256) ? 256 : k; }
  const bool j4ok = (lane == 0);

  for (int tile = 0; tile < 5; ++tile) {
    const int s0 = tile * 64;
    const int nrows = (Ss - s0) < 64 ? (Ss - s0) : 64;
    __syncthreads();
    // stage K
    for (int e = tid; e < Ss*64; e += 512) {
      const int row = e >> 6, f = e & 63;
      kv[row*66 + f] = bf2f(kbf[base + (size_t)row*Dd + f]);
    }
    __syncthreads();

    // ---- scores + softmax: wave owns 8 q rows
    if (wave*8 < nrows) {
      float acc[8][5];
#pragma unroll
      for (int r = 0; r < 8; ++r)
#pragma unroll
        for (int j = 0; j < 5; ++j) acc[r][j] = 0.f;
      const float* qp[8];
#pragma unroll
      for (int r = 0; r < 8; ++r) {
        int srow = s0 + wave*8 + r; if (srow > 256) srow = 256;
        qp[r] = q + base + (size_t)srow * Dd;
      }
      int kbase[5];
#pragma unroll
      for (int j = 0; j < 5; ++j) kbase[j] = kk[j]*66;

      for (int f = 0; f < 64; f += 2) {
        float2 kf[5];
#pragma unroll
        for (int j = 0; j < 5; ++j) kf[j] = *(const float2*)&kv[kbase[j] + f];
#pragma unroll
        for (int r = 0; r < 8; ++r) {
          const float2 qv = *(const float2*)(qp[r] + f);
#pragma unroll
          for (int j = 0; j < 5; ++j) {
            acc[r][j] = fmaf(qv.x, kf[j].x, acc[r][j]);
            acc[r][j] = fmaf(qv.y, kf[j].y, acc[r][j]);
          }
        }
      }

#pragma unroll
      for (int r = 0; r < 8; ++r) {
        const int srow = s0 + wave*8 + r;
        if (srow <= 256) {
          float sc[5];
#pragma unroll
          for (int j = 0; j < 5; ++j) sc[j] = acc[r][j] * 0.125f;
          if (!j4ok) sc[4] = -1e30f;
          float mx = fmaxf(fmaxf(fmaxf(sc[0], sc[1]), fmaxf(sc[2], sc[3])), sc[4]);
#pragma unroll
          for (int d = 1; d < 64; d <<= 1) mx = fmaxf(mx, __shfl_xor(mx, d));
          float pj[5]; float sum = 0.f;
#pragma unroll
          for (int j = 0; j < 5; ++j) { pj[j] = __expf(sc[j] - mx); sum += pj[j]; }
#pragma unroll
          for (int d = 1; d < 64; d <<= 1) sum += __shfl_xor(sum, d);
          const float inv = 1.f / sum;
          if (srow == 0) {   // entropy reweighting of query row 0 (post-softmax)
#pragma unroll
            for (int j = 0; j < 5; ++j) {
              const float ef = (kk[j] == 0) ? 1.f : ent[(size_t)bh*256 + (kk[j] - 1)];
              pj[j] *= ef;
            }
          }
          float* prow = &plds[(wave*8 + r) * 260];
#pragma unroll
          for (int j = 0; j < 4; ++j) prow[lane + 64*j] = pj[j] * inv;
          if (lane < 4) prow[256 + lane] = j4ok ? pj[4] * inv : 0.f;
        }
      }
    }
    __syncthreads();
    // stage V (overwrite kv), zero tail rows 257..259
    for (int e = tid; e < 260*64; e += 512) {
      const int row = e >> 6, f = e & 63;
      kv[row*68 + f] = (row < Ss) ? bf2f(vbf[base + (size_t)row*Dd + f]) : 0.f;
    }
    __syncthreads();

    // ---- PV: 8 waves = 4 k-groups x 2 row-groups
    const int kg = wave >> 1, rg = wave & 1;
    const int tx = lane & 15, tyy = lane >> 4;
    float pv[8][4];
#pragma unroll
    for (int i = 0; i < 8; ++i)
#pragma unroll
      for (int jj = 0; jj < 4; ++jj) pv[i][jj] = 0.f;
    for (int g2 = kg; g2 <= 64; g2 += 4) {
      const int k0 = g2 * 4;
      float4 v4[4];
#pragma unroll
      for (int kx = 0; kx < 4; ++kx) v4[kx] = *(const float4*)&kv[(k0 + kx)*68 + tx*4];
#pragma unroll
      for (int i = 0; i < 8; ++i) {
        const float4 p4 = *(const float4*)&plds[(rg*32 + tyy*8 + i)*260 + k0];
        const float pa[4] = {p4.x, p4.y, p4.z, p4.w};
#pragma unroll
        for (int kx = 0; kx < 4; ++kx) {
          pv[i][0] = fmaf(pa[kx], v4[kx].x, pv[i][0]);
          pv[i][1] = fmaf(pa[kx], v4[kx].y, pv[i][1]);
          pv[i][2] = fmaf(pa[kx], v4[kx].z, pv[i][2]);
          pv[i][3] = fmaf(pa[kx], v4[kx].w, pv[i][3]);
        }
      }
    }
    __syncthreads();
    float* red = plds;   // reuse
    if (kg > 0) {
      const int rbase = (((kg - 1)*2 + rg)*64 + lane)*32;
#pragma unroll
      for (int i = 0; i < 8; ++i)
#pragma unroll
        for (int jj = 0; jj < 4; ++jj) red[rbase + i*4 + jj] = pv[i][jj];
    }
    __syncthreads();
    if (kg == 0) {
#pragma unroll
      for (int kgo = 0; kgo < 3; ++kgo) {
        const int rbase = ((kgo*2 + rg)*64 + lane)*32;
#pragma unroll
        for (int i = 0; i < 8; ++i)
#pragma unroll
          for (int jj = 0; jj < 4; ++jj) pv[i][jj] += red[rbase + i*4 + jj];
      }
#pragma unroll
      for (int i = 0; i < 8; ++i) {
        const int r = rg*32 + tyy*8 + i;
        if (r < nrows) {
          ushort4 o;
          o.x = f2bf(pv[i][0]); o.y = f2bf(pv[i][1]);
          o.z = f2bf(pv[i][2]); o.w = f2bf(pv[i][3]);
          *(ushort4*)(ctxb + base + (size_t)(s0 + r)*Dd + tx*4) = o;
        }
      }
    }
  }
}

// ---------------------------------------------------------------------------
extern "C" void kernel_launch(void* const* d_in, const int* in_sizes, int n_in,
                              void* d_out, int out_size, void* d_ws, size_t ws_size,
                              hipStream_t stream) {
  const float* hid = (const float*)d_in[0];
  const float* Wq  = (const float*)d_in[1];
  const float* bq  = (const float*)d_in[2];
  const float* Wk  = (const float*)d_in[3];
  const float* bk  = (const float*)d_in[4];
  const float* Wv  = (const float*)d_in[5];
  const float* bv  = (const float*)d_in[6];
  const float* Wo  = (const float*)d_in[7];
  const float* bo  = (const float*)d_in[8];
  const float* A1  = (const float*)d_in[9];
  const float* a1  = (const float*)d_in[10];
  const float* A2  = (const float*)d_in[11];
  const float* a2  = (const float*)d_in[12];
  const float* B1  = (const float*)d_in[13];
  const float* b1  = (const float*)d_in[14];
  const float* B2  = (const float*)d_in[15];
  const float* b2  = (const float*)d_in[16];

  char* p = (char*)d_ws;
  size_t off = 0;
  auto alloc = [&](size_t bytes) -> void* {
    void* r = p + off; off += (bytes + 255) & ~(size_t)255; return r;
  };
  u16*   hb   = (u16*)  alloc((size_t)M2*Dd*2);
  u16*   wqt  = (u16*)  alloc((size_t)Dd*Dd*2);
  u16*   wkt  = (u16*)  alloc((size_t)Dd*Dd*2);
  u16*   wvt  = (u16*)  alloc((size_t)Dd*Dd*2);
  u16*   wot  = (u16*)  alloc((size_t)Dd*Dd*2);
  float* qf   = (float*)alloc((size_t)M2*Dd*4);
  u16*   kb   = (u16*)  alloc((size_t)M2*Dd*2);
  u16*   vb   = (u16*)  alloc((size_t)M2*Dd*2);
  u16*   ctxb = (u16*)  alloc((size_t)M2*Dd*2);
  float* entw = (float*)alloc((size_t)Bb*Hh*256*4);
  float* lossw = (float*)alloc(256);
  u16*   a1tb = (u16*)  alloc((size_t)NADH*HDd*2);      // A1t [512][64] bf16
  u16*   b1tb = (u16*)  alloc((size_t)NADH*4*HDd*2);    // B1t [512][256] bf16

  hipMemsetAsync(lossw, 0, 4, stream);
  k_conv_hidden<<<dim3((M2*Dd/4)/256), 256, 0, stream>>>(hid, hb);
  dim3 tg(24, 24);
  k_tconv<<<tg, 256, 0, stream>>>(Wq, wqt, Dd, Dd);
  k_tconv<<<tg, 256, 0, stream>>>(Wk, wkt, Dd, Dd);
  k_tconv<<<tg, 256, 0, stream>>>(Wv, wvt, Dd, Dd);
  k_tconv<<<tg, 256, 0, stream>>>(Wo, wot, Dd, Dd);
  k_tconv<<<dim3(16, 2), 256, 0, stream>>>(A1, a1tb, HDd, NADH);
  k_tconv<<<dim3(16, 8), 256, 0, stream>>>(B1, b1tb, 4*HDd, NADH);
  dim3 gg(129, 6);
  k_gemm<0><<<gg, 256, 0, stream>>>(hb, wqt, bq, qf, Mv, nullptr, nullptr);
  k_gemm<1><<<gg, 256, 0, stream>>>(hb, wkt, bk, kb, Mv, nullptr, nullptr);
  k_gemm<1><<<gg, 256, 0, stream>>>(hb, wvt, bv, vb, Mv, nullptr, nullptr);
  k_adv2<<<Bb*Hh, 256, 0, stream>>>(kb, a1tb, a1, A2, a2, b1tb, b1, B2, b2, entw, lossw);
  k_attn<<<Bb*Hh, 512, 0, stream>>>(qf, kb, vb, entw, ctxb);
  k_gemm<0><<<gg, 256, 0, stream>>>(ctxb, wot, bo, (float*)d_out, Mv,
                                    lossw, ((float*)d_out) + (size_t)Mv*Dd);
}

// Round 5
// 570.256 us; speedup vs baseline: 3.0713x; 1.6259x over previous
//
#include <hip/hip_runtime.h>

// Problem constants
#define Bb   64
#define Ss   257
#define Hh   12
#define HDd  64
#define Dd   768
#define Mv   16448        // B*S
#define M2   16512        // 129*128 (padded rows for 128-tiles)
#define NADH 512

typedef unsigned short u16;
typedef float  f32x4 __attribute__((ext_vector_type(4)));
typedef short  s16x8 __attribute__((ext_vector_type(8)));
typedef short  s16x4 __attribute__((ext_vector_type(4)));

__device__ __forceinline__ float bf2f(u16 u) {
  unsigned x = ((unsigned)u) << 16;
  return __builtin_bit_cast(float, x);
}
__device__ __forceinline__ u16 f2bf(float f) {
  unsigned x = __builtin_bit_cast(unsigned, f);
  x = x + 0x7fffu + ((x >> 16) & 1u);   // RNE
  return (u16)(x >> 16);
}

// ---------------------------------------------------------------------------
// hidden (Mv x 768 f32) -> bf16, zero-padded to M2 rows
__global__ void k_conv_hidden(const float* __restrict__ src, u16* __restrict__ dst) {
  size_t i4 = (size_t)blockIdx.x * 256 + threadIdx.x;
  size_t e = i4 * 4;
  size_t row = e / Dd;
  float4 v = make_float4(0.f, 0.f, 0.f, 0.f);
  if (row < Mv) v = *(const float4*)(src + e);
  ushort4 o;
  o.x = f2bf(v.x); o.y = f2bf(v.y); o.z = f2bf(v.z); o.w = f2bf(v.w);
  *(ushort4*)(dst + e) = o;
}

// W (K x N f32, [k][n]) -> Wt bf16 [n][k]
__global__ void k_tconv(const float* __restrict__ W, u16* __restrict__ Wt,
                        int K, int N) {
  __shared__ float tile[32][33];
  const int tx = threadIdx.x & 31, ty = threadIdx.x >> 5;  // 32 x 8
  const int n0 = blockIdx.x * 32, k0 = blockIdx.y * 32;
#pragma unroll
  for (int i = 0; i < 4; ++i)
    tile[ty + i*8][tx] = W[(size_t)(k0 + ty + i*8)*N + n0 + tx];
  __syncthreads();
#pragma unroll
  for (int i = 0; i < 4; ++i)
    Wt[(size_t)(n0 + ty + i*8)*K + k0 + tx] = f2bf(tile[tx][ty + i*8]);
}

// ---------------------------------------------------------------------------
// bf16 MFMA GEMM: C[M2 x 768] = A[M2 x 768] @ Wt^T + bias (m97-style 128x128)
template<int OUTBF16>
__global__ __launch_bounds__(256) void k_gemm(
    const u16* __restrict__ A, const u16* __restrict__ Bt,
    const float* __restrict__ bias, void* __restrict__ Cout,
    int Mvalid, const float* lossbuf, float* lossout)
{
  const int N = Dd, K = Dd;
  __shared__ u16 As[128*32];
  __shared__ u16 Bs[128*32];
  const int tid = threadIdx.x;
  const int lane = tid & 63, wave = tid >> 6;
  const int m0 = blockIdx.x * 128, n0 = blockIdx.y * 128;

  if (lossout && blockIdx.x == 0 && blockIdx.y == 0 && tid == 0)
    lossout[0] = lossbuf[0];

  const int arow0 = tid >> 2,        auc = tid & 3;
  const int arow1 = (tid >> 2) + 64;
  const u16* agp0 = A  + (size_t)(m0 + arow0) * K + auc * 8;
  const u16* agp1 = A  + (size_t)(m0 + arow1) * K + auc * 8;
  const u16* bgp0 = Bt + (size_t)(n0 + arow0) * K + auc * 8;
  const u16* bgp1 = Bt + (size_t)(n0 + arow1) * K + auc * 8;
  u16* asp0 = As + (arow0*4 + (auc ^ (arow0 & 3))) * 8;
  u16* asp1 = As + (arow1*4 + (auc ^ (arow1 & 3))) * 8;
  u16* bsp0 = Bs + (arow0*4 + (auc ^ (arow0 & 3))) * 8;
  u16* bsp1 = Bs + (arow1*4 + (auc ^ (arow1 & 3))) * 8;

  f32x4 acc[4][4];
#pragma unroll
  for (int i = 0; i < 4; ++i)
#pragma unroll
    for (int j = 0; j < 4; ++j) acc[i][j] = f32x4{0.f, 0.f, 0.f, 0.f};

  const int wr = wave >> 1, wc = wave & 1;
  const int fr = lane & 15, g = lane >> 4;
  const s16x8* afp[4];
  const s16x8* bfp[4];
#pragma unroll
  for (int mi = 0; mi < 4; ++mi) {
    const int rowa = wr*64 + mi*16 + fr;
    afp[mi] = (const s16x8*)(As + (rowa*4 + (g ^ (rowa & 3))) * 8);
    const int rowb = wc*64 + mi*16 + fr;
    bfp[mi] = (const s16x8*)(Bs + (rowb*4 + (g ^ (rowb & 3))) * 8);
  }

  s16x8 ra0 = *(const s16x8*)agp0;
  s16x8 ra1 = *(const s16x8*)agp1;
  s16x8 rb0 = *(const s16x8*)bgp0;
  s16x8 rb1 = *(const s16x8*)bgp1;

  for (int kt = 0; kt < K/32; ++kt) {
    __syncthreads();
    *(s16x8*)asp0 = ra0; *(s16x8*)asp1 = ra1;
    *(s16x8*)bsp0 = rb0; *(s16x8*)bsp1 = rb1;
    __syncthreads();
    if (kt + 1 < K/32) {
      const int o = (kt + 1) * 32;
      ra0 = *(const s16x8*)(agp0 + o);
      ra1 = *(const s16x8*)(agp1 + o);
      rb0 = *(const s16x8*)(bgp0 + o);
      rb1 = *(const s16x8*)(bgp1 + o);
    }
    s16x8 af[4], bf[4];
#pragma unroll
    for (int mi = 0; mi < 4; ++mi) af[mi] = afp[mi][0];
#pragma unroll
    for (int ni = 0; ni < 4; ++ni) bf[ni] = bfp[ni][0];
#pragma unroll
    for (int mi = 0; mi < 4; ++mi)
#pragma unroll
      for (int ni = 0; ni < 4; ++ni)
        acc[mi][ni] = __builtin_amdgcn_mfma_f32_16x16x32_bf16(af[mi], bf[ni], acc[mi][ni], 0, 0, 0);
  }

  // epilogue: C/D layout col = lane&15, row = (lane>>4)*4 + reg
#pragma unroll
  for (int ni = 0; ni < 4; ++ni) {
    const int col = n0 + wc*64 + ni*16 + fr;
    const float bv = bias[col];
#pragma unroll
    for (int mi = 0; mi < 4; ++mi) {
      const int rowb = m0 + wr*64 + mi*16 + (lane >> 4)*4;
#pragma unroll
      for (int r = 0; r < 4; ++r) {
        const int row = rowb + r;
        if (row < Mvalid) {
          const float vv = acc[mi][ni][r] + bv;
          if (OUTBF16) ((u16*)Cout)[(size_t)row*N + col] = f2bf(vv);
          else         ((float*)Cout)[(size_t)row*N + col] = vv;
        }
      }
    }
  }
}

// ---------------------------------------------------------------------------
// Adversarial MLPs via MFMA (passing).
__global__ __launch_bounds__(256) void k_adv2(
    const u16* __restrict__ kbf,
    const u16* __restrict__ A1t, const float* __restrict__ a1,
    const float* __restrict__ A2, const float* __restrict__ a2,
    const u16* __restrict__ B1t, const float* __restrict__ b1,
    const float* __restrict__ B2, const float* __restrict__ b2,
    float* __restrict__ ent, float* __restrict__ lossacc)
{
  __shared__ u16  pb[2048*8];
  __shared__ float p1s[256], l1s[256];
  __shared__ float s2part[4*64];
  __shared__ float p2s[64], l2s[64];
  __shared__ float red[256];

  const int tid = threadIdx.x;
  const int lane = tid & 63, wave = tid >> 6;
  const int fr = lane & 15, g = lane >> 4;
  const int bh = blockIdx.x;
  const int b = bh / Hh, h = bh % Hh;
  const size_t base = (size_t)b * Ss * Dd + (size_t)h * HDd;

#pragma unroll
  for (int it = 0; it < 8; ++it) {
    const int u = it*256 + tid;
    const int row = u >> 3, c = u & 7;
    const s16x8 v = *(const s16x8*)(kbf + base + (size_t)(1 + row)*Dd + c*8);
    *(s16x8*)(pb + (row*8 + (c ^ (row & 7)))*8) = v;
  }
  __syncthreads();

  // ---- phase A
  {
    s16x8 af[4][2];
#pragma unroll
    for (int mi = 0; mi < 4; ++mi)
#pragma unroll
      for (int kt = 0; kt < 2; ++kt) {
        const int row = wave*64 + mi*16 + fr;
        const int c = kt*4 + g;
        af[mi][kt] = *(const s16x8*)(pb + (row*8 + (c ^ (row & 7)))*8);
      }
    float sp[4][4];
#pragma unroll
    for (int mi = 0; mi < 4; ++mi)
#pragma unroll
      for (int r = 0; r < 4; ++r) sp[mi][r] = 0.f;

    for (int ni = 0; ni < 32; ++ni) {
      const int col = ni*16 + fr;
      f32x4 acc[4];
#pragma unroll
      for (int mi = 0; mi < 4; ++mi) acc[mi] = f32x4{0.f,0.f,0.f,0.f};
#pragma unroll
      for (int kt = 0; kt < 2; ++kt) {
        const s16x8 bfr = *(const s16x8*)(A1t + (size_t)col*64 + kt*32 + g*8);
#pragma unroll
        for (int mi = 0; mi < 4; ++mi)
          acc[mi] = __builtin_amdgcn_mfma_f32_16x16x32_bf16(af[mi][kt], bfr, acc[mi], 0, 0, 0);
      }
      const float c1v = a1[col], w2 = A2[col];
#pragma unroll
      for (int mi = 0; mi < 4; ++mi)
#pragma unroll
        for (int r = 0; r < 4; ++r)
          sp[mi][r] += fmaxf(acc[mi][r] + c1v, 0.f) * w2;
    }
#pragma unroll
    for (int mi = 0; mi < 4; ++mi)
#pragma unroll
      for (int r = 0; r < 4; ++r) {
        float v = sp[mi][r];
        v += __shfl_xor(v, 1); v += __shfl_xor(v, 2);
        v += __shfl_xor(v, 4); v += __shfl_xor(v, 8);
        if (fr == 0) {
          const int row = wave*64 + mi*16 + g*4 + r;
          const float z1 = v + a2[0];
          const float q = 1.f / (1.f + __expf(z1));
          p1s[row] = 1.f - q;
          l1s[row] = -__logf(fmaxf(q, 1e-10f));
        }
      }
  }

  // ---- phase B
#pragma unroll
  for (int pass = 0; pass < 2; ++pass) {
    s16x8 am[2][8];
#pragma unroll
    for (int mi = 0; mi < 2; ++mi)
#pragma unroll
      for (int kt2 = 0; kt2 < 8; ++kt2) {
        const int m = (pass*2 + mi)*16 + fr;
        const int p = kt2 >> 1;
        const int prow = (m >> 3)*32 + (m & 7)*2 + (p >> 1)*16 + (p & 1);
        const int c = (kt2 & 1)*4 + g;
        am[mi][kt2] = *(const s16x8*)(pb + (prow*8 + (c ^ (prow & 7)))*8);
      }
    float sp2[2][4];
#pragma unroll
    for (int mi = 0; mi < 2; ++mi)
#pragma unroll
      for (int r = 0; r < 4; ++r) sp2[mi][r] = 0.f;

    for (int ni2 = 0; ni2 < 8; ++ni2) {
      const int col = wave*128 + ni2*16 + fr;
      f32x4 acc[2];
#pragma unroll
      for (int mi = 0; mi < 2; ++mi) acc[mi] = f32x4{0.f,0.f,0.f,0.f};
#pragma unroll
      for (int kt2 = 0; kt2 < 8; ++kt2) {
        const s16x8 bfr = *(const s16x8*)(B1t + (size_t)col*256 + kt2*32 + g*8);
#pragma unroll
        for (int mi = 0; mi < 2; ++mi)
          acc[mi] = __builtin_amdgcn_mfma_f32_16x16x32_bf16(am[mi][kt2], bfr, acc[mi], 0, 0, 0);
      }
      const float c1v = b1[col], w2 = B2[col];
#pragma unroll
      for (int mi = 0; mi < 2; ++mi)
#pragma unroll
        for (int r = 0; r < 4; ++r)
          sp2[mi][r] += fmaxf(acc[mi][r] + c1v, 0.f) * w2;
    }
#pragma unroll
    for (int mi = 0; mi < 2; ++mi)
#pragma unroll
      for (int r = 0; r < 4; ++r) {
        float v = sp2[mi][r];
        v += __shfl_xor(v, 1); v += __shfl_xor(v, 2);
        v += __shfl_xor(v, 4); v += __shfl_xor(v, 8);
        if (fr == 0) {
          const int m = (pass*2 + mi)*16 + g*4 + r;
          s2part[wave*64 + m] = v;
        }
      }
  }
  __syncthreads();
  if (tid < 64) {
    const float z2 = s2part[tid] + s2part[64 + tid] + s2part[128 + tid]
                   + s2part[192 + tid] + b2[0];
    const float q = 1.f / (1.f + __expf(z2));
    p2s[tid] = 1.f - q;
    l2s[tid] = -__logf(fmaxf(q, 1e-10f));
  }
  __syncthreads();

  const int rr = tid >> 4, cc2 = tid & 15;
  const float p2g = p2s[(rr >> 1)*8 + (cc2 >> 1)];
  const float p1v = p1s[tid];
  const float ad  = 0.525f*p1v + 0.475f*p2g;
  const float entv = -ad*__log2f(ad + 1e-10f) - (1.f - ad)*__log2f(1.f - ad + 1e-10f);
  ent[(size_t)bh*256 + tid] = entv;

  float lc = l1s[tid] * (1.f/196608.f);
  if (tid < 64) lc += l2s[tid] * (1.f/49152.f);
  red[tid] = lc;
  __syncthreads();
  for (int s = 128; s > 0; s >>= 1) {
    if (tid < s) red[tid] += red[tid + s];
    __syncthreads();
  }
  if (tid == 0) atomicAdd(lossacc, red[0]);
}

// ---------------------------------------------------------------------------
// MFMA flash attention. One block per (b,h), 4 waves. Swapped QK^T
// (mfma(K,Q)): lane (fr,g) reg r holds P[q-row fr][k=16ct+4g+r] -> packed
// bf16 P stays in registers as the PV A-fragment. V stored TRANSPOSED in LDS
// (Vt[d][k], LD=292) so the PV B-fragment is two plain ds_read_b64 with the
// identical k-slot order (same-permutation argument as the passing k_gemm).
__global__ __launch_bounds__(256) void k_attn2(
    const u16* __restrict__ qb, const u16* __restrict__ kbf, const u16* __restrict__ vbf,
    const float* __restrict__ entp, u16* __restrict__ ctxb)
{
#define VLD 292
  __shared__ u16 Vt[64*VLD];   // 37376 B; Vt[d*VLD + k], k zero-padded to 288
  const int tid = threadIdx.x;
  const int lane = tid & 63, wave = tid >> 6;
  const int fr = lane & 15, g = lane >> 4;
  const int bh = blockIdx.x;
  const int b = bh / Hh, h = bh % Hh;
  const size_t base = (size_t)b * Ss * Dd + (size_t)h * HDd;

  // stage V transposed (zero k>=257)
  for (int c = tid; c < 2304; c += 256) {   // 288 k-rows x 8 d-chunks
    const int k = c >> 3, dc = c & 7;
    s16x8 v = s16x8{0,0,0,0,0,0,0,0};
    if (k < Ss) v = *(const s16x8*)(vbf + base + (size_t)k * Dd + dc * 8);
#pragma unroll
    for (int i = 0; i < 8; ++i) Vt[(dc*8 + i)*VLD + k] = (u16)v[i];
  }
  __syncthreads();

  for (int pi = 0; pi < 5; ++pi) {
    if (pi == 4 && wave != 0) break;
    const int rb = (pi == 4) ? 16 : pi*4 + wave;   // 17 row-blocks of 16 q-rows
    const int q0 = rb * 16;

    const u16* qr = qb + base + (size_t)(q0 + fr)*Dd + g*8;
    const s16x8 qf0 = *(const s16x8*)qr;
    const s16x8 qf1 = *(const s16x8*)(qr + 32);

    f32x4 acc[18];
#pragma unroll
    for (int ct = 0; ct < 18; ++ct) acc[ct] = f32x4{0.f,0.f,0.f,0.f};
#pragma unroll
    for (int ct = 0; ct < 18; ++ct) {
      const u16* kr = kbf + base + (size_t)(ct*16 + fr)*Dd + g*8;
      const s16x8 kf0 = *(const s16x8*)kr;
      const s16x8 kf1 = *(const s16x8*)(kr + 32);
      acc[ct] = __builtin_amdgcn_mfma_f32_16x16x32_bf16(kf0, qf0, acc[ct], 0, 0, 0);
      acc[ct] = __builtin_amdgcn_mfma_f32_16x16x32_bf16(kf1, qf1, acc[ct], 0, 0, 0);
    }

    // lane (fr,g) reg r holds scores[k = 16ct+4g+r][q-row = fr]
    float mx = -3e38f;
#pragma unroll
    for (int ct = 0; ct < 18; ++ct)
#pragma unroll
      for (int r = 0; r < 4; ++r) {
        const int k = ct*16 + g*4 + r;
        float s = acc[ct][r] * 0.125f;
        if (k >= Ss) s = -1e30f;
        acc[ct][r] = s;
        mx = fmaxf(mx, s);
      }
    mx = fmaxf(mx, __shfl_xor(mx, 16));
    mx = fmaxf(mx, __shfl_xor(mx, 32));
    float sum = 0.f;
#pragma unroll
    for (int ct = 0; ct < 18; ++ct)
#pragma unroll
      for (int r = 0; r < 4; ++r) {
        const float p = __expf(acc[ct][r] - mx);
        acc[ct][r] = p;
        sum += p;
      }
    sum += __shfl_xor(sum, 16);
    sum += __shfl_xor(sum, 32);
    const float inv = 1.f / sum;

    // entropy reweighting of q-row 0 (post-softmax, no renorm)
    if (rb == 0 && fr == 0) {
#pragma unroll
      for (int ct = 0; ct < 17; ++ct)
#pragma unroll
        for (int r = 0; r < 4; ++r) {
          const int k = ct*16 + g*4 + r;
          if (k > 0 && k < Ss) acc[ct][r] *= entp[(size_t)bh*256 + k - 1];
        }
    }

    unsigned pk[18][2];
#pragma unroll
    for (int ct = 0; ct < 18; ++ct) {
      pk[ct][0] = (unsigned)f2bf(acc[ct][0]*inv) | ((unsigned)f2bf(acc[ct][1]*inv) << 16);
      pk[ct][1] = (unsigned)f2bf(acc[ct][2]*inv) | ((unsigned)f2bf(acc[ct][3]*inv) << 16);
    }

    f32x4 o[4];
#pragma unroll
    for (int dt = 0; dt < 4; ++dt) o[dt] = f32x4{0.f,0.f,0.f,0.f};

#pragma unroll
    for (int kt = 0; kt < 9; ++kt) {
      // A-fragment: P slots k = 32kt + {4g+0..3, 16+4g+0..3} (q-row = fr)
      const unsigned au0 = pk[2*kt][0], au1 = pk[2*kt][1];
      const unsigned au2 = pk[2*kt+1][0], au3 = pk[2*kt+1][1];
      s16x8 af;
      af[0] = (short)(au0 & 0xffff); af[1] = (short)(au0 >> 16);
      af[2] = (short)(au1 & 0xffff); af[3] = (short)(au1 >> 16);
      af[4] = (short)(au2 & 0xffff); af[5] = (short)(au2 >> 16);
      af[6] = (short)(au3 & 0xffff); af[7] = (short)(au3 >> 16);
#pragma unroll
      for (int dt = 0; dt < 4; ++dt) {
        // B-fragment: V[k same slots][d = dt*16+fr]
        const int hw = (dt*16 + fr)*VLD + kt*32 + g*4;
        const s16x4 lo = *(const s16x4*)(Vt + hw);
        const s16x4 hi = *(const s16x4*)(Vt + hw + 16);
        const s16x8 bf = {lo[0],lo[1],lo[2],lo[3],hi[0],hi[1],hi[2],hi[3]};
        o[dt] = __builtin_amdgcn_mfma_f32_16x16x32_bf16(af, bf, o[dt], 0, 0, 0);
      }
    }

    // output: lane (fr,g) reg r holds ctx[q0 + g*4+r][dt*16 + fr]
#pragma unroll
    for (int r = 0; r < 4; ++r) {
      const int row = q0 + g*4 + r;
      if (row < Ss) {
#pragma unroll
        for (int dt = 0; dt < 4; ++dt)
          ctxb[base + (size_t)row*Dd + dt*16 + fr] = f2bf(o[dt][r]);
      }
    }
  }
#undef VLD
}

// ---------------------------------------------------------------------------
extern "C" void kernel_launch(void* const* d_in, const int* in_sizes, int n_in,
                              void* d_out, int out_size, void* d_ws, size_t ws_size,
                              hipStream_t stream) {
  const float* hid = (const float*)d_in[0];
  const float* Wq  = (const float*)d_in[1];
  const float* bq  = (const float*)d_in[2];
  const float* Wk  = (const float*)d_in[3];
  const float* bk  = (const float*)d_in[4];
  const float* Wv  = (const float*)d_in[5];
  const float* bv  = (const float*)d_in[6];
  const float* Wo  = (const float*)d_in[7];
  const float* bo  = (const float*)d_in[8];
  const float* A1  = (const float*)d_in[9];
  const float* a1  = (const float*)d_in[10];
  const float* A2  = (const float*)d_in[11];
  const float* a2  = (const float*)d_in[12];
  const float* B1  = (const float*)d_in[13];
  const float* b1  = (const float*)d_in[14];
  const float* B2  = (const float*)d_in[15];
  const float* b2  = (const float*)d_in[16];

  char* p = (char*)d_ws;
  size_t off = 0;
  auto alloc = [&](size_t bytes) -> void* {
    void* r = p + off; off += (bytes + 255) & ~(size_t)255; return r;
  };
  u16*   hb   = (u16*)  alloc((size_t)M2*Dd*2);
  u16*   wqt  = (u16*)  alloc((size_t)Dd*Dd*2);
  u16*   wkt  = (u16*)  alloc((size_t)Dd*Dd*2);
  u16*   wvt  = (u16*)  alloc((size_t)Dd*Dd*2);
  u16*   wot  = (u16*)  alloc((size_t)Dd*Dd*2);
  u16*   qbb  = (u16*)  alloc((size_t)M2*Dd*2);
  u16*   kb   = (u16*)  alloc((size_t)M2*Dd*2);
  u16*   vb   = (u16*)  alloc((size_t)M2*Dd*2);
  u16*   ctxb = (u16*)  alloc((size_t)M2*Dd*2);
  float* entw = (float*)alloc((size_t)Bb*Hh*256*4);
  float* lossw = (float*)alloc(256);
  u16*   a1tb = (u16*)  alloc((size_t)NADH*HDd*2);      // A1t [512][64] bf16
  u16*   b1tb = (u16*)  alloc((size_t)NADH*4*HDd*2);    // B1t [512][256] bf16

  hipMemsetAsync(lossw, 0, 4, stream);
  k_conv_hidden<<<dim3((M2*Dd/4)/256), 256, 0, stream>>>(hid, hb);
  dim3 tg(24, 24);
  k_tconv<<<tg, 256, 0, stream>>>(Wq, wqt, Dd, Dd);
  k_tconv<<<tg, 256, 0, stream>>>(Wk, wkt, Dd, Dd);
  k_tconv<<<tg, 256, 0, stream>>>(Wv, wvt, Dd, Dd);
  k_tconv<<<tg, 256, 0, stream>>>(Wo, wot, Dd, Dd);
  k_tconv<<<dim3(16, 2), 256, 0, stream>>>(A1, a1tb, HDd, NADH);
  k_tconv<<<dim3(16, 8), 256, 0, stream>>>(B1, b1tb, 4*HDd, NADH);
  dim3 gg(129, 6);
  k_gemm<1><<<gg, 256, 0, stream>>>(hb, wqt, bq, qbb, Mv, nullptr, nullptr);
  k_gemm<1><<<gg, 256, 0, stream>>>(hb, wkt, bk, kb, Mv, nullptr, nullptr);
  k_gemm<1><<<gg, 256, 0, stream>>>(hb, wvt, bv, vb, Mv, nullptr, nullptr);
  k_adv2<<<Bb*Hh, 256, 0, stream>>>(kb, a1tb, a1, A2, a2, b1tb, b1, B2, b2, entw, lossw);
  k_attn2<<<Bb*Hh, 256, 0, stream>>>(qbb, kb, vb, entw, ctxb);
  k_gemm<0><<<gg, 256, 0, stream>>>(ctxb, wot, bo, (float*)d_out, Mv,
                                    lossw, ((float*)d_out) + (size_t)Mv*Dd);
}